// Round 5
// baseline (3547.577 us; speedup 1.0000x reference)
//
#include <hip/hip_runtime.h>

// K-means assignment via split-fp16 MFMA GEMM + fused argmin.
// d2 = x2 + c2 - 2*x.cT ; x = hi+lo (fp16 each); dot = hh + hl + lh on
// mfma_f32_16x16x32_f16 (fp32 accum).
// Round-5: keep round-3's register-prefetch pipeline + LDK=40 padded LDS, but
// restore round-2's BIT-EXACT epilogue numerics (in-block x2, s=x2+cv, v=s-2acc,
// c2 via the verbatim row_norms_kernel). Rounds 3/4 failed on O(1) knife-edge
// tie rows: perturbing the argmin-invariant x2 term flips rows whose top-2
// distance gap < fp32 ulp(~1024) ~ 6e-5. Every scalar-visible value here is
// bit-identical to round 2's passing kernel.

#define N_PTS 131072
#define K_CL  2048
#define D_DIM 512
#define BM 128
#define BN 128
#define BK 32
#define LDK 40   // padded LDS row stride in f16 (80 B)
#define NIT ((K_CL / BN) * (D_DIM / BK))   // 256

typedef _Float16 half8  __attribute__((ext_vector_type(8)));
typedef _Float16 half4v __attribute__((ext_vector_type(4)));
typedef float    floatx4 __attribute__((ext_vector_type(4)));

// ---- c2 norms: one wave per row (VERBATIM round-2 kernel; bit-proven) ----
__global__ void row_norms_kernel(const float* __restrict__ A,
                                 float* __restrict__ out, int rows) {
    int gid  = blockIdx.x * blockDim.x + threadIdx.x;
    int wave = gid >> 6;
    int lane = gid & 63;
    if (wave >= rows) return;
    const float4* a = (const float4*)(A + (size_t)wave * D_DIM);
    float4 p = a[lane];
    float4 q = a[lane + 64];
    float s = p.x*p.x + p.y*p.y + p.z*p.z + p.w*p.w
            + q.x*q.x + q.y*q.y + q.z*q.z + q.w*q.w;
    #pragma unroll
    for (int off = 32; off > 0; off >>= 1) s += __shfl_down(s, off, 64);
    if (lane == 0) out[wave] = s;
}

// ---- fp32 -> (hi,lo) fp16 planes; one wave per row ----
__global__ void conv_f16x2_kernel(const float* __restrict__ src,
                                  _Float16* __restrict__ hi,
                                  _Float16* __restrict__ lo, int rows) {
    int gid = blockIdx.x * blockDim.x + threadIdx.x;
    int row = gid >> 6, lane = gid & 63;
    if (row >= rows) return;
    const float4* a = (const float4*)(src + (size_t)row * D_DIM);
    float4 p = a[lane];        // d = lane*4
    float4 q = a[lane + 64];   // d = 256 + lane*4
    half4v ph, pl, qh, ql;
    ph.x=(_Float16)p.x; ph.y=(_Float16)p.y; ph.z=(_Float16)p.z; ph.w=(_Float16)p.w;
    qh.x=(_Float16)q.x; qh.y=(_Float16)q.y; qh.z=(_Float16)q.z; qh.w=(_Float16)q.w;
    pl.x=(_Float16)(p.x-(float)ph.x); pl.y=(_Float16)(p.y-(float)ph.y);
    pl.z=(_Float16)(p.z-(float)ph.z); pl.w=(_Float16)(p.w-(float)ph.w);
    ql.x=(_Float16)(q.x-(float)qh.x); ql.y=(_Float16)(q.y-(float)qh.y);
    ql.z=(_Float16)(q.z-(float)qh.z); ql.w=(_Float16)(q.w-(float)qh.w);
    *(half4v*)(hi + (size_t)row * D_DIM +       lane * 4) = ph;
    *(half4v*)(hi + (size_t)row * D_DIM + 256 + lane * 4) = qh;
    *(half4v*)(lo + (size_t)row * D_DIM +       lane * 4) = pl;
    *(half4v*)(lo + (size_t)row * D_DIM + 256 + lane * 4) = ql;
}

// ---- main: 128x128 block, register-prefetch pipeline, fused argmin ----
// PRE: operands pre-converted in ws. !PRE: self-contained fallback.
template<bool PRE>
__global__ __launch_bounds__(256, 3)
void kmeans_mfma(const float* __restrict__ X, const float* __restrict__ C,
                 const _Float16* __restrict__ Xhi, const _Float16* __restrict__ Xlo,
                 const _Float16* __restrict__ Chi, const _Float16* __restrict__ Clo,
                 const float* __restrict__ c2g, int* __restrict__ out) {
    __shared__ __align__(16) _Float16 sXh[BM * LDK], sXl[BM * LDK];
    __shared__ __align__(16) _Float16 sCh[BN * LDK], sCl[BN * LDK];
    __shared__ float c2s[K_CL];   // 8 KB
    __shared__ float x2s[BM];     // LDS total ~50 KB -> 3 blocks/CU

    const int tid  = threadIdx.x;
    const int lane = tid & 63;
    const int w    = tid >> 6;    // wave 0..3
    const int wti  = w >> 1;      // row half
    const int wtj  = w & 1;       // col half
    const int q    = lane >> 4;   // quad
    const int m16  = lane & 15;
    const int rowBase = blockIdx.x * BM;

    // c2 into LDS
    if (PRE) {
        #pragma unroll
        for (int i = tid; i < K_CL / 4; i += 256)
            ((float4*)c2s)[i] = ((const float4*)c2g)[i];
    } else {
        for (int k = tid; k < K_CL; k += 256) {
            const float4* cp = (const float4*)(C + (size_t)k * D_DIM);
            float s0 = 0.f, s1 = 0.f;
            for (int j = 0; j < D_DIM / 4; j += 2) {
                float4 a = cp[j], b = cp[j + 1];
                s0 += a.x*a.x + a.y*a.y + a.z*a.z + a.w*a.w;
                s1 += b.x*b.x + b.y*b.y + b.z*b.z + b.w*b.w;
            }
            c2s[k] = s0 + s1;
        }
    }
    // x2 into LDS — VERBATIM round-2 in-block code (bit-exact epilogue input).
    {
        int r = tid & 127, h = tid >> 7;
        const float4* xp = (const float4*)(X + (size_t)(rowBase + r) * D_DIM + h * 256);
        float s0 = 0.f, s1 = 0.f;
        for (int j = 0; j < 64; j += 2) {
            float4 a = xp[j], b = xp[j + 1];
            s0 += a.x*a.x + a.y*a.y + a.z*a.z + a.w*a.w;
            s1 += b.x*b.x + b.y*b.y + b.z*b.z + b.w*b.w;
        }
        ((float*)sXh)[tid] = s0 + s1;
    }
    __syncthreads();
    if (tid < BM) x2s[tid] = ((float*)sXh)[tid] + ((float*)sXh)[tid + 128];
    // sXh scratch reads complete before first store_tiles: covered by barrier (A).

    float bestV[4][4];
    int   bestI[4][4];
    #pragma unroll
    for (int ti = 0; ti < 4; ++ti)
        #pragma unroll
        for (int r = 0; r < 4; ++r) { bestV[ti][r] = 3.4e38f; bestI[ti][r] = 0; }

    // staging map: thread -> rows {s_row, s_row+64}, 16B granule s_f4
    const int s_row = tid >> 2;
    const int s_f4  = tid & 3;

    float4 rXh[2], rXl[2], rCh[2], rCl[2];

    auto prefetch = [&](int nit) {
        const int nkt = nit >> 4, ndt = nit & 15;
        const int d0 = ndt * BK + s_f4 * 8;
        #pragma unroll
        for (int u = 0; u < 2; ++u) {
            size_t xr = (size_t)(rowBase + s_row + u * 64) * D_DIM + d0;
            size_t cr = (size_t)(nkt * BN + s_row + u * 64) * D_DIM + d0;
            if (PRE) {
                rXh[u] = *(const float4*)(Xhi + xr);
                rXl[u] = *(const float4*)(Xlo + xr);
                rCh[u] = *(const float4*)(Chi + cr);
                rCl[u] = *(const float4*)(Clo + cr);
            } else {
                rXh[u] = *(const float4*)(X + xr);
                rXl[u] = *(const float4*)(X + xr + 4);
                rCh[u] = *(const float4*)(C + cr);
                rCl[u] = *(const float4*)(C + cr + 4);
            }
        }
    };

    auto store_tiles = [&]() {
        #pragma unroll
        for (int u = 0; u < 2; ++u) {
            int r = s_row + u * 64;
            if (PRE) {
                *(float4*)&sXh[r * LDK + s_f4 * 8] = rXh[u];
                *(float4*)&sXl[r * LDK + s_f4 * 8] = rXl[u];
                *(float4*)&sCh[r * LDK + s_f4 * 8] = rCh[u];
                *(float4*)&sCl[r * LDK + s_f4 * 8] = rCl[u];
            } else {
                float fx[8] = {rXh[u].x, rXh[u].y, rXh[u].z, rXh[u].w,
                               rXl[u].x, rXl[u].y, rXl[u].z, rXl[u].w};
                float fc[8] = {rCh[u].x, rCh[u].y, rCh[u].z, rCh[u].w,
                               rCl[u].x, rCl[u].y, rCl[u].z, rCl[u].w};
                half8 xh, xl, ch, cl;
                #pragma unroll
                for (int j = 0; j < 8; ++j) {
                    xh[j] = (_Float16)fx[j]; xl[j] = (_Float16)(fx[j] - (float)xh[j]);
                    ch[j] = (_Float16)fc[j]; cl[j] = (_Float16)(fc[j] - (float)ch[j]);
                }
                *(half8*)&sXh[r * LDK + s_f4 * 8] = xh;
                *(half8*)&sXl[r * LDK + s_f4 * 8] = xl;
                *(half8*)&sCh[r * LDK + s_f4 * 8] = ch;
                *(half8*)&sCl[r * LDK + s_f4 * 8] = cl;
            }
        }
    };

    floatx4 acc[4][4];
    #pragma unroll
    for (int ti = 0; ti < 4; ++ti)
        #pragma unroll
        for (int tj = 0; tj < 4; ++tj) acc[ti][tj] = (floatx4){0.f, 0.f, 0.f, 0.f};

    prefetch(0);

    #pragma unroll 1
    for (int it = 0; it < NIT; ++it) {
        __syncthreads();               // (A) prior iter's tile reads complete
        store_tiles();                 // regs -> LDS
        __syncthreads();               // (B) tiles visible
        if (it + 1 < NIT) prefetch(it + 1);   // overlaps MFMA phase below

        // MFMA phase. A frag: A[m=lane&15][k=quad*8+j]
        half8 ah[4], al[4];
        #pragma unroll
        for (int ti = 0; ti < 4; ++ti) {
            int row = wti * 64 + ti * 16 + m16;
            ah[ti] = *(const half8*)&sXh[row * LDK + q * 8];
            al[ti] = *(const half8*)&sXl[row * LDK + q * 8];
        }
        #pragma unroll
        for (int tj = 0; tj < 4; ++tj) {
            int col = wtj * 64 + tj * 16 + m16;
            half8 bh = *(const half8*)&sCh[col * LDK + q * 8];
            half8 bl = *(const half8*)&sCl[col * LDK + q * 8];
            #pragma unroll
            for (int ti = 0; ti < 4; ++ti) {
                floatx4 a = acc[ti][tj];
                a = __builtin_amdgcn_mfma_f32_16x16x32_f16(ah[ti], bh, a, 0, 0, 0);
                a = __builtin_amdgcn_mfma_f32_16x16x32_f16(ah[ti], bl, a, 0, 0, 0);
                a = __builtin_amdgcn_mfma_f32_16x16x32_f16(al[ti], bh, a, 0, 0, 0);
                acc[ti][tj] = a;
            }
        }

        // end of col-tile: fused argmin epilogue (VERBATIM round-2 math:
        // s = x2 + cv; v = s - 2*acc), reset acc. D layout: col=lane&15,
        // row=quad*4+reg. cols ascend + strict '<' => first-occurrence ties.
        if ((it & 15) == 15) {
            const int k0 = (it >> 4) * BN;
            #pragma unroll
            for (int tj = 0; tj < 4; ++tj) {
                int col = k0 + wtj * 64 + tj * 16 + m16;
                float cv = c2s[col];
                #pragma unroll
                for (int ti = 0; ti < 4; ++ti)
                    #pragma unroll
                    for (int r = 0; r < 4; ++r) {
                        float s = x2s[wti * 64 + ti * 16 + q * 4 + r] + cv;
                        float v = s - 2.0f * acc[ti][tj][r];
                        if (v < bestV[ti][r]) { bestV[ti][r] = v; bestI[ti][r] = col; }
                        acc[ti][tj][r] = 0.0f;
                    }
            }
        }
    }

    // cross-lane reduce over the 16 lanes sharing each row (lexicographic)
    #pragma unroll
    for (int ti = 0; ti < 4; ++ti)
        #pragma unroll
        for (int r = 0; r < 4; ++r) {
            float v = bestV[ti][r]; int ix = bestI[ti][r];
            #pragma unroll
            for (int off = 1; off < 16; off <<= 1) {
                float ov = __shfl_xor(v, off, 64);
                int   oi = __shfl_xor(ix, off, 64);
                if (ov < v || (ov == v && oi < ix)) { v = ov; ix = oi; }
            }
            bestV[ti][r] = v; bestI[ti][r] = ix;
        }

    __syncthreads();                   // tiles dead; reuse as scratch
    float* rv  = (float*)sXh;          // [128][2]
    int*   rix = (int*)sCh;            // [128][2]
    if (m16 == 0) {
        #pragma unroll
        for (int ti = 0; ti < 4; ++ti)
            #pragma unroll
            for (int r = 0; r < 4; ++r) {
                int rloc = wti * 64 + ti * 16 + q * 4 + r;
                rv[rloc * 2 + wtj]  = bestV[ti][r];
                rix[rloc * 2 + wtj] = bestI[ti][r];
            }
    }
    __syncthreads();
    if (tid < BM) {
        float v0 = rv[tid * 2], v1 = rv[tid * 2 + 1];
        int   i0 = rix[tid * 2], i1 = rix[tid * 2 + 1];
        out[rowBase + tid] = (v1 < v0 || (v1 == v0 && i1 < i0)) ? i1 : i0;
    }
}

extern "C" void kernel_launch(void* const* d_in, const int* in_sizes, int n_in,
                              void* d_out, int out_size, void* d_ws, size_t ws_size,
                              hipStream_t stream) {
    const float* X = (const float*)d_in[0];   // [N, D]
    const float* C = (const float*)d_in[1];   // [K, D]
    int* out = (int*)d_out;

    char* ws = (char*)d_ws;
    const size_t c2_off  = 0;
    const size_t chi_off = (size_t)K_CL * 4;                        // 8 KB
    const size_t clo_off = chi_off + (size_t)K_CL * D_DIM * 2;      // +2 MB
    const size_t xhi_off = clo_off + (size_t)K_CL * D_DIM * 2;      // +2 MB
    const size_t xlo_off = xhi_off + (size_t)N_PTS * D_DIM * 2;     // +128 MB
    const size_t need_full = xlo_off + (size_t)N_PTS * D_DIM * 2;   // 272,637,952

    if (ws_size >= need_full) {
        float*    c2  = (float*)(ws + c2_off);
        _Float16* Chi = (_Float16*)(ws + chi_off);
        _Float16* Clo = (_Float16*)(ws + clo_off);
        _Float16* Xhi = (_Float16*)(ws + xhi_off);
        _Float16* Xlo = (_Float16*)(ws + xlo_off);
        row_norms_kernel<<<(K_CL * 64) / 256, 256, 0, stream>>>(C, c2, K_CL);
        conv_f16x2_kernel<<<(K_CL * 64) / 256, 256, 0, stream>>>(C, Chi, Clo, K_CL);
        conv_f16x2_kernel<<<(N_PTS * 64) / 256, 256, 0, stream>>>(X, Xhi, Xlo, N_PTS);
        kmeans_mfma<true><<<N_PTS / BM, 256, 0, stream>>>(
            X, C, Xhi, Xlo, Chi, Clo, c2, out);
    } else {
        // self-contained fallback: no ws use at all (correct, just slower)
        kmeans_mfma<false><<<N_PTS / BM, 256, 0, stream>>>(
            X, C, nullptr, nullptr, nullptr, nullptr, nullptr, out);
    }
}

// Round 6
// 1528.341 us; speedup vs baseline: 2.3212x; 2.3212x over previous
//
#include <hip/hip_runtime.h>

// K-means assignment via split-fp16 MFMA GEMM + fused argmin.
// d2 = x2 + c2 - 2*x.cT ; x = hi+lo (fp16 each); dot = hh + hl + lh on
// mfma_f32_16x16x32_f16 (fp32 accum).
// Round-6: numerics bit-identical to round 5 (passed, absmax 0). Only change:
// staging buffers are 8 named float4 locals + macro-expanded prefetch/store
// (round 5's lambda-captured arrays were spilled to scratch -> 7.5 GB of
// WRITE_SIZE and a 3.2x regression; named vectors promote to VGPRs).

#define N_PTS 131072
#define K_CL  2048
#define D_DIM 512
#define BM 128
#define BN 128
#define BK 32
#define LDK 40   // padded LDS row stride in f16 (80 B)
#define NIT ((K_CL / BN) * (D_DIM / BK))   // 256

typedef _Float16 half8  __attribute__((ext_vector_type(8)));
typedef _Float16 half4v __attribute__((ext_vector_type(4)));
typedef float    floatx4 __attribute__((ext_vector_type(4)));

// ---- c2 norms: one wave per row (VERBATIM round-2 kernel; bit-proven) ----
__global__ void row_norms_kernel(const float* __restrict__ A,
                                 float* __restrict__ out, int rows) {
    int gid  = blockIdx.x * blockDim.x + threadIdx.x;
    int wave = gid >> 6;
    int lane = gid & 63;
    if (wave >= rows) return;
    const float4* a = (const float4*)(A + (size_t)wave * D_DIM);
    float4 p = a[lane];
    float4 q = a[lane + 64];
    float s = p.x*p.x + p.y*p.y + p.z*p.z + p.w*p.w
            + q.x*q.x + q.y*q.y + q.z*q.z + q.w*q.w;
    #pragma unroll
    for (int off = 32; off > 0; off >>= 1) s += __shfl_down(s, off, 64);
    if (lane == 0) out[wave] = s;
}

// ---- fp32 -> (hi,lo) fp16 planes; one wave per row ----
__global__ void conv_f16x2_kernel(const float* __restrict__ src,
                                  _Float16* __restrict__ hi,
                                  _Float16* __restrict__ lo, int rows) {
    int gid = blockIdx.x * blockDim.x + threadIdx.x;
    int row = gid >> 6, lane = gid & 63;
    if (row >= rows) return;
    const float4* a = (const float4*)(src + (size_t)row * D_DIM);
    float4 p = a[lane];        // d = lane*4
    float4 q = a[lane + 64];   // d = 256 + lane*4
    half4v ph, pl, qh, ql;
    ph.x=(_Float16)p.x; ph.y=(_Float16)p.y; ph.z=(_Float16)p.z; ph.w=(_Float16)p.w;
    qh.x=(_Float16)q.x; qh.y=(_Float16)q.y; qh.z=(_Float16)q.z; qh.w=(_Float16)q.w;
    pl.x=(_Float16)(p.x-(float)ph.x); pl.y=(_Float16)(p.y-(float)ph.y);
    pl.z=(_Float16)(p.z-(float)ph.z); pl.w=(_Float16)(p.w-(float)ph.w);
    ql.x=(_Float16)(q.x-(float)qh.x); ql.y=(_Float16)(q.y-(float)qh.y);
    ql.z=(_Float16)(q.z-(float)qh.z); ql.w=(_Float16)(q.w-(float)qh.w);
    *(half4v*)(hi + (size_t)row * D_DIM +       lane * 4) = ph;
    *(half4v*)(hi + (size_t)row * D_DIM + 256 + lane * 4) = qh;
    *(half4v*)(lo + (size_t)row * D_DIM +       lane * 4) = pl;
    *(half4v*)(lo + (size_t)row * D_DIM + 256 + lane * 4) = ql;
}

// prefetch next tile granules into 8 named float4 regs (PRE path)
#define PREFETCH_PRE(nit) do {                                          \
    const int nkt_ = (nit) >> 4, ndt_ = (nit) & 15;                     \
    const int d0_ = ndt_ * BK + s_f4 * 8;                               \
    size_t xr0_ = (size_t)(rowBase + s_row) * D_DIM + d0_;              \
    size_t xr1_ = xr0_ + (size_t)64 * D_DIM;                            \
    size_t cr0_ = (size_t)(nkt_ * BN + s_row) * D_DIM + d0_;            \
    size_t cr1_ = cr0_ + (size_t)64 * D_DIM;                            \
    rXh0 = *(const float4*)(Xhi + xr0_);                                \
    rXh1 = *(const float4*)(Xhi + xr1_);                                \
    rXl0 = *(const float4*)(Xlo + xr0_);                                \
    rXl1 = *(const float4*)(Xlo + xr1_);                                \
    rCh0 = *(const float4*)(Chi + cr0_);                                \
    rCh1 = *(const float4*)(Chi + cr1_);                                \
    rCl0 = *(const float4*)(Clo + cr0_);                                \
    rCl1 = *(const float4*)(Clo + cr1_);                                \
} while (0)

// prefetch raw fp32 (8 floats per granule) into the same regs (!PRE path)
#define PREFETCH_RAW(nit) do {                                          \
    const int nkt_ = (nit) >> 4, ndt_ = (nit) & 15;                     \
    const int d0_ = ndt_ * BK + s_f4 * 8;                               \
    size_t xr0_ = (size_t)(rowBase + s_row) * D_DIM + d0_;              \
    size_t xr1_ = xr0_ + (size_t)64 * D_DIM;                            \
    size_t cr0_ = (size_t)(nkt_ * BN + s_row) * D_DIM + d0_;            \
    size_t cr1_ = cr0_ + (size_t)64 * D_DIM;                            \
    rXh0 = *(const float4*)(X + xr0_);  rXl0 = *(const float4*)(X + xr0_ + 4); \
    rXh1 = *(const float4*)(X + xr1_);  rXl1 = *(const float4*)(X + xr1_ + 4); \
    rCh0 = *(const float4*)(C + cr0_);  rCl0 = *(const float4*)(C + cr0_ + 4); \
    rCh1 = *(const float4*)(C + cr1_);  rCl1 = *(const float4*)(C + cr1_ + 4); \
} while (0)

// fp32x8 (in two float4) -> hi/lo half8, elementwise split
#define SPLIT8(h_, l_, v0_, v1_) do {                                   \
    h_[0]=(_Float16)v0_.x; h_[1]=(_Float16)v0_.y;                       \
    h_[2]=(_Float16)v0_.z; h_[3]=(_Float16)v0_.w;                       \
    h_[4]=(_Float16)v1_.x; h_[5]=(_Float16)v1_.y;                       \
    h_[6]=(_Float16)v1_.z; h_[7]=(_Float16)v1_.w;                       \
    l_[0]=(_Float16)(v0_.x-(float)h_[0]); l_[1]=(_Float16)(v0_.y-(float)h_[1]); \
    l_[2]=(_Float16)(v0_.z-(float)h_[2]); l_[3]=(_Float16)(v0_.w-(float)h_[3]); \
    l_[4]=(_Float16)(v1_.x-(float)h_[4]); l_[5]=(_Float16)(v1_.y-(float)h_[5]); \
    l_[6]=(_Float16)(v1_.z-(float)h_[6]); l_[7]=(_Float16)(v1_.w-(float)h_[7]); \
} while (0)

// ---- main: 128x128 block, register-prefetch pipeline, fused argmin ----
template<bool PRE>
__global__ __launch_bounds__(256, 3)
void kmeans_mfma(const float* __restrict__ X, const float* __restrict__ C,
                 const _Float16* __restrict__ Xhi, const _Float16* __restrict__ Xlo,
                 const _Float16* __restrict__ Chi, const _Float16* __restrict__ Clo,
                 const float* __restrict__ c2g, int* __restrict__ out) {
    __shared__ __align__(16) _Float16 sXh[BM * LDK], sXl[BM * LDK];
    __shared__ __align__(16) _Float16 sCh[BN * LDK], sCl[BN * LDK];
    __shared__ float c2s[K_CL];   // 8 KB
    __shared__ float x2s[BM];     // LDS total ~50 KB -> 3 blocks/CU

    const int tid  = threadIdx.x;
    const int lane = tid & 63;
    const int w    = tid >> 6;    // wave 0..3
    const int wti  = w >> 1;      // row half
    const int wtj  = w & 1;       // col half
    const int q    = lane >> 4;   // quad
    const int m16  = lane & 15;
    const int rowBase = blockIdx.x * BM;

    // c2 into LDS
    if (PRE) {
        #pragma unroll
        for (int i = tid; i < K_CL / 4; i += 256)
            ((float4*)c2s)[i] = ((const float4*)c2g)[i];
    } else {
        for (int k = tid; k < K_CL; k += 256) {
            const float4* cp = (const float4*)(C + (size_t)k * D_DIM);
            float s0 = 0.f, s1 = 0.f;
            for (int j = 0; j < D_DIM / 4; j += 2) {
                float4 a = cp[j], b = cp[j + 1];
                s0 += a.x*a.x + a.y*a.y + a.z*a.z + a.w*a.w;
                s1 += b.x*b.x + b.y*b.y + b.z*b.z + b.w*b.w;
            }
            c2s[k] = s0 + s1;
        }
    }
    // x2 into LDS — VERBATIM round-2/5 in-block code (bit-exact epilogue input).
    {
        int r = tid & 127, h = tid >> 7;
        const float4* xp = (const float4*)(X + (size_t)(rowBase + r) * D_DIM + h * 256);
        float s0 = 0.f, s1 = 0.f;
        for (int j = 0; j < 64; j += 2) {
            float4 a = xp[j], b = xp[j + 1];
            s0 += a.x*a.x + a.y*a.y + a.z*a.z + a.w*a.w;
            s1 += b.x*b.x + b.y*b.y + b.z*b.z + b.w*b.w;
        }
        ((float*)sXh)[tid] = s0 + s1;
    }
    __syncthreads();
    if (tid < BM) x2s[tid] = ((float*)sXh)[tid] + ((float*)sXh)[tid + 128];
    // sXh scratch reads complete before first store: covered by barrier (A).

    float bestV[4][4];
    int   bestI[4][4];
    #pragma unroll
    for (int ti = 0; ti < 4; ++ti)
        #pragma unroll
        for (int r = 0; r < 4; ++r) { bestV[ti][r] = 3.4e38f; bestI[ti][r] = 0; }

    // staging map: thread -> rows {s_row, s_row+64}, 16B granule s_f4
    const int s_row = tid >> 2;
    const int s_f4  = tid & 3;

    // named staging regs (NOT arrays / lambdas: round-5 spilled to scratch)
    float4 rXh0, rXh1, rXl0, rXl1, rCh0, rCh1, rCl0, rCl1;

    floatx4 acc[4][4];
    #pragma unroll
    for (int ti = 0; ti < 4; ++ti)
        #pragma unroll
        for (int tj = 0; tj < 4; ++tj) acc[ti][tj] = (floatx4){0.f, 0.f, 0.f, 0.f};

    if (PRE) PREFETCH_PRE(0); else PREFETCH_RAW(0);

    #pragma unroll 1
    for (int it = 0; it < NIT; ++it) {
        __syncthreads();               // (A) prior iter's tile reads complete
        // regs -> LDS
        {
            const int r0 = s_row, r1 = s_row + 64;
            if (PRE) {
                *(float4*)&sXh[r0 * LDK + s_f4 * 8] = rXh0;
                *(float4*)&sXh[r1 * LDK + s_f4 * 8] = rXh1;
                *(float4*)&sXl[r0 * LDK + s_f4 * 8] = rXl0;
                *(float4*)&sXl[r1 * LDK + s_f4 * 8] = rXl1;
                *(float4*)&sCh[r0 * LDK + s_f4 * 8] = rCh0;
                *(float4*)&sCh[r1 * LDK + s_f4 * 8] = rCh1;
                *(float4*)&sCl[r0 * LDK + s_f4 * 8] = rCl0;
                *(float4*)&sCl[r1 * LDK + s_f4 * 8] = rCl1;
            } else {
                half8 h, l;
                SPLIT8(h, l, rXh0, rXl0);
                *(half8*)&sXh[r0 * LDK + s_f4 * 8] = h;
                *(half8*)&sXl[r0 * LDK + s_f4 * 8] = l;
                SPLIT8(h, l, rXh1, rXl1);
                *(half8*)&sXh[r1 * LDK + s_f4 * 8] = h;
                *(half8*)&sXl[r1 * LDK + s_f4 * 8] = l;
                SPLIT8(h, l, rCh0, rCl0);
                *(half8*)&sCh[r0 * LDK + s_f4 * 8] = h;
                *(half8*)&sCl[r0 * LDK + s_f4 * 8] = l;
                SPLIT8(h, l, rCh1, rCl1);
                *(half8*)&sCh[r1 * LDK + s_f4 * 8] = h;
                *(half8*)&sCl[r1 * LDK + s_f4 * 8] = l;
            }
        }
        __syncthreads();               // (B) tiles visible

        // prefetch next iteration (overlaps the MFMA phase below)
        if (it + 1 < NIT) {
            if (PRE) PREFETCH_PRE(it + 1); else PREFETCH_RAW(it + 1);
        }

        // MFMA phase. A frag: A[m=lane&15][k=quad*8+j]
        half8 ah[4], al[4];
        #pragma unroll
        for (int ti = 0; ti < 4; ++ti) {
            int row = wti * 64 + ti * 16 + m16;
            ah[ti] = *(const half8*)&sXh[row * LDK + q * 8];
            al[ti] = *(const half8*)&sXl[row * LDK + q * 8];
        }
        #pragma unroll
        for (int tj = 0; tj < 4; ++tj) {
            int col = wtj * 64 + tj * 16 + m16;
            half8 bh = *(const half8*)&sCh[col * LDK + q * 8];
            half8 bl = *(const half8*)&sCl[col * LDK + q * 8];
            #pragma unroll
            for (int ti = 0; ti < 4; ++ti) {
                floatx4 a = acc[ti][tj];
                a = __builtin_amdgcn_mfma_f32_16x16x32_f16(ah[ti], bh, a, 0, 0, 0);
                a = __builtin_amdgcn_mfma_f32_16x16x32_f16(ah[ti], bl, a, 0, 0, 0);
                a = __builtin_amdgcn_mfma_f32_16x16x32_f16(al[ti], bh, a, 0, 0, 0);
                acc[ti][tj] = a;
            }
        }

        // end of col-tile: fused argmin epilogue (VERBATIM round-2/5 math:
        // s = x2 + cv; v = s - 2*acc), reset acc. D layout: col=lane&15,
        // row=quad*4+reg. cols ascend + strict '<' => first-occurrence ties.
        if ((it & 15) == 15) {
            const int k0 = (it >> 4) * BN;
            #pragma unroll
            for (int tj = 0; tj < 4; ++tj) {
                int col = k0 + wtj * 64 + tj * 16 + m16;
                float cv = c2s[col];
                #pragma unroll
                for (int ti = 0; ti < 4; ++ti)
                    #pragma unroll
                    for (int r = 0; r < 4; ++r) {
                        float s = x2s[wti * 64 + ti * 16 + q * 4 + r] + cv;
                        float v = s - 2.0f * acc[ti][tj][r];
                        if (v < bestV[ti][r]) { bestV[ti][r] = v; bestI[ti][r] = col; }
                        acc[ti][tj][r] = 0.0f;
                    }
            }
        }
    }

    // cross-lane reduce over the 16 lanes sharing each row (lexicographic)
    #pragma unroll
    for (int ti = 0; ti < 4; ++ti)
        #pragma unroll
        for (int r = 0; r < 4; ++r) {
            float v = bestV[ti][r]; int ix = bestI[ti][r];
            #pragma unroll
            for (int off = 1; off < 16; off <<= 1) {
                float ov = __shfl_xor(v, off, 64);
                int   oi = __shfl_xor(ix, off, 64);
                if (ov < v || (ov == v && oi < ix)) { v = ov; ix = oi; }
            }
            bestV[ti][r] = v; bestI[ti][r] = ix;
        }

    __syncthreads();                   // tiles dead; reuse as scratch
    float* rv  = (float*)sXh;          // [128][2]
    int*   rix = (int*)sCh;            // [128][2]
    if (m16 == 0) {
        #pragma unroll
        for (int ti = 0; ti < 4; ++ti)
            #pragma unroll
            for (int r = 0; r < 4; ++r) {
                int rloc = wti * 64 + ti * 16 + q * 4 + r;
                rv[rloc * 2 + wtj]  = bestV[ti][r];
                rix[rloc * 2 + wtj] = bestI[ti][r];
            }
    }
    __syncthreads();
    if (tid < BM) {
        float v0 = rv[tid * 2], v1 = rv[tid * 2 + 1];
        int   i0 = rix[tid * 2], i1 = rix[tid * 2 + 1];
        out[rowBase + tid] = (v1 < v0 || (v1 == v0 && i1 < i0)) ? i1 : i0;
    }
}

extern "C" void kernel_launch(void* const* d_in, const int* in_sizes, int n_in,
                              void* d_out, int out_size, void* d_ws, size_t ws_size,
                              hipStream_t stream) {
    const float* X = (const float*)d_in[0];   // [N, D]
    const float* C = (const float*)d_in[1];   // [K, D]
    int* out = (int*)d_out;

    char* ws = (char*)d_ws;
    const size_t c2_off  = 0;
    const size_t chi_off = (size_t)K_CL * 4;                        // 8 KB
    const size_t clo_off = chi_off + (size_t)K_CL * D_DIM * 2;      // +2 MB
    const size_t xhi_off = clo_off + (size_t)K_CL * D_DIM * 2;      // +2 MB
    const size_t xlo_off = xhi_off + (size_t)N_PTS * D_DIM * 2;     // +128 MB
    const size_t need_full = xlo_off + (size_t)N_PTS * D_DIM * 2;   // 272,637,952

    if (ws_size >= need_full) {
        float*    c2  = (float*)(ws + c2_off);
        _Float16* Chi = (_Float16*)(ws + chi_off);
        _Float16* Clo = (_Float16*)(ws + clo_off);
        _Float16* Xhi = (_Float16*)(ws + xhi_off);
        _Float16* Xlo = (_Float16*)(ws + xlo_off);
        row_norms_kernel<<<(K_CL * 64) / 256, 256, 0, stream>>>(C, c2, K_CL);
        conv_f16x2_kernel<<<(K_CL * 64) / 256, 256, 0, stream>>>(C, Chi, Clo, K_CL);
        conv_f16x2_kernel<<<(N_PTS * 64) / 256, 256, 0, stream>>>(X, Xhi, Xlo, N_PTS);
        kmeans_mfma<true><<<N_PTS / BM, 256, 0, stream>>>(
            X, C, Xhi, Xlo, Chi, Clo, c2, out);
    } else {
        // self-contained fallback: no ws use at all (correct, just slower)
        kmeans_mfma<false><<<N_PTS / BM, 256, 0, stream>>>(
            X, C, nullptr, nullptr, nullptr, nullptr, nullptr, out);
    }
}